// Round 16
// baseline (235.395 us; speedup 1.0000x reference)
//
#include <hip/hip_runtime.h>
#include <math.h>

typedef __bf16 bf16x8 __attribute__((ext_vector_type(8)));
typedef __bf16 bf16x4 __attribute__((ext_vector_type(4)));
typedef float  f32x4  __attribute__((ext_vector_type(4)));

// ---------------------------------------------------------------------------
// cvt: fp32 -> bf16 for the 4 weight matrices (512x512 each)
// ---------------------------------------------------------------------------
__global__ __launch_bounds__(256)
void cvt_w(const float* __restrict__ w0, const float* __restrict__ w1,
           const float* __restrict__ w2, const float* __restrict__ w3,
           __bf16* __restrict__ d0, __bf16* __restrict__ d1,
           __bf16* __restrict__ d2, __bf16* __restrict__ d3)
{
    const int y = blockIdx.y;
    const float* s = (y == 0) ? w0 : (y == 1) ? w1 : (y == 2) ? w2 : w3;
    __bf16*      d = (y == 0) ? d0 : (y == 1) ? d1 : (y == 2) ? d2 : d3;
    const int i = blockIdx.x * 256 + threadIdx.x;
    float4 a = *(const float4*)(s + (size_t)i * 8);
    float4 b = *(const float4*)(s + (size_t)i * 8 + 4);
    bf16x8 v;
    v[0] = (__bf16)a.x; v[1] = (__bf16)a.y; v[2] = (__bf16)a.z; v[3] = (__bf16)a.w;
    v[4] = (__bf16)b.x; v[5] = (__bf16)b.y; v[6] = (__bf16)b.z; v[7] = (__bf16)b.w;
    *(bf16x8*)(d + (size_t)i * 8) = v;
}

// ---------------------------------------------------------------------------
// Fused QKV projection, z-merged (R8-proven, +9us): one block computes Q, K
// and V for its tile; X loaded once per k-chunk feeds all three MFMA sets.
// ---------------------------------------------------------------------------
__global__ __launch_bounds__(256, 2)
void qkv_proj(const float* __restrict__ X,
              const __bf16* __restrict__ Wqb, const __bf16* __restrict__ Wkb,
              const __bf16* __restrict__ Wvb,
              const float* __restrict__ bq, const float* __restrict__ bk,
              const float* __restrict__ bv,
              __bf16* __restrict__ qTb, __bf16* __restrict__ kTb,
              __bf16* __restrict__ vTb)
{
    const int tid  = threadIdx.x;
    const int w    = tid >> 6;
    const int lane = tid & 63;
    const int lq   = lane & 15;
    const int quad = lane >> 4;
    const int n0    = blockIdx.x * 64 + (w >> 1) * 32;
    const int obase = blockIdx.y * 128 + (w & 1) * 64;

    const __bf16* const Wz[3] = { Wqb, Wkb, Wvb };

    f32x4 acc[3][2][4] = {};
    for (int k0 = 0; k0 < 512; k0 += 32) {
        bf16x8 af[2];
#pragma unroll
        for (int m = 0; m < 2; m++) {
            const float* xp = X + (size_t)(n0 + m * 16 + lq) * 512 + k0 + quad * 8;
            float4 x0 = *(const float4*)xp;
            float4 x1 = *(const float4*)(xp + 4);
            bf16x8 v;
            v[0] = (__bf16)x0.x; v[1] = (__bf16)x0.y; v[2] = (__bf16)x0.z; v[3] = (__bf16)x0.w;
            v[4] = (__bf16)x1.x; v[5] = (__bf16)x1.y; v[6] = (__bf16)x1.z; v[7] = (__bf16)x1.w;
            af[m] = v;
        }
#pragma unroll
        for (int z = 0; z < 3; z++) {
            bf16x8 bfr[4];
#pragma unroll
            for (int nn = 0; nn < 4; nn++)
                bfr[nn] = *(const bf16x8*)(Wz[z] + (size_t)(obase + nn * 16 + lq) * 512 + k0 + quad * 8);
#pragma unroll
            for (int m = 0; m < 2; m++)
#pragma unroll
                for (int nn = 0; nn < 4; nn++)
                    acc[z][m][nn] = __builtin_amdgcn_mfma_f32_16x16x32_bf16(af[m], bfr[nn], acc[z][m][nn], 0, 0, 0);
        }
    }

    const float* const ba[3] = { bq, bk, bv };
    const float scaling = 0.17677669529663687f;
#pragma unroll
    for (int z = 0; z < 3; z++)
#pragma unroll
        for (int m = 0; m < 2; m++)
#pragma unroll
            for (int nn = 0; nn < 4; nn++)
#pragma unroll
                for (int r = 0; r < 4; r++) {
                    const int n = n0 + m * 16 + quad * 4 + r;
                    const int o = obase + nn * 16 + lq;
                    float val = acc[z][m][nn][r] + ba[z][o];
                    const int t = n >> 2, b = n & 3;
                    const int h = o >> 5, d = o & 31;
                    const int bh = b * 16 + h;
                    if (z == 0)
                        qTb[(((size_t)bh * 1024 + t) << 5) + d] = (__bf16)(val * scaling);
                    else if (z == 1)
                        kTb[(((size_t)bh * 1024 + t) << 5) + d] = (__bf16)val;
                    else
                        vTb[(((size_t)bh * 32 + d) << 10) + t] = (__bf16)val;
                }
}

// ---------------------------------------------------------------------------
// Out projection (y<4) with fused avg merge (y>=4, replaces avg_add launch).
// ---------------------------------------------------------------------------
__global__ __launch_bounds__(256)
void out_proj(const __bf16* __restrict__ A, const __bf16* __restrict__ Wb,
              const float* __restrict__ bias, float* __restrict__ out,
              float* __restrict__ avg, const __bf16* __restrict__ p1)
{
    if (blockIdx.y >= 4) {
        // avg_out += p1 (bf16 partial). (64x32) blocks x 256 thr x 8 = 4194304
        const size_t i = ((size_t)((blockIdx.y - 4) * 64 + blockIdx.x) * 256 +
                          threadIdx.x) * 8;
        bf16x8 a = *(const bf16x8*)(p1 + i);
        float4 lo = *(float4*)(avg + i);
        float4 hi = *(float4*)(avg + i + 4);
        lo.x += (float)a[0]; lo.y += (float)a[1];
        lo.z += (float)a[2]; lo.w += (float)a[3];
        hi.x += (float)a[4]; hi.y += (float)a[5];
        hi.z += (float)a[6]; hi.w += (float)a[7];
        *(float4*)(avg + i)     = lo;
        *(float4*)(avg + i + 4) = hi;
        return;
    }

    const int tid  = threadIdx.x;
    const int w    = tid >> 6;
    const int lane = tid & 63;
    const int lq   = lane & 15;
    const int quad = lane >> 4;
    const int n0    = blockIdx.x * 64 + (w >> 1) * 32;
    const int obase = blockIdx.y * 128 + (w & 1) * 64;

    f32x4 acc[2][4] = {};
    for (int k0 = 0; k0 < 512; k0 += 32) {
        bf16x8 af[2], bfr[4];
#pragma unroll
        for (int m = 0; m < 2; m++)
            af[m] = *(const bf16x8*)(A + (size_t)(n0 + m * 16 + lq) * 512 + k0 + quad * 8);
#pragma unroll
        for (int nn = 0; nn < 4; nn++)
            bfr[nn] = *(const bf16x8*)(Wb + (size_t)(obase + nn * 16 + lq) * 512 + k0 + quad * 8);
#pragma unroll
        for (int m = 0; m < 2; m++)
#pragma unroll
            for (int nn = 0; nn < 4; nn++)
                acc[m][nn] = __builtin_amdgcn_mfma_f32_16x16x32_bf16(af[m], bfr[nn], acc[m][nn], 0, 0, 0);
    }
#pragma unroll
    for (int m = 0; m < 2; m++)
#pragma unroll
        for (int nn = 0; nn < 4; nn++)
#pragma unroll
            for (int r = 0; r < 4; r++) {
                const int n = n0 + m * 16 + quad * 4 + r;
                const int o = obase + nn * 16 + lq;
                out[(size_t)n * 512 + o] = acc[m][nn][r] + bias[o];
            }
}

// ---------------------------------------------------------------------------
// MFMA attention, 16-WAVE build: live set fits under the hard 128-VGPR cap.
//
// R14 proved spill relief is the real gradient (-32 regs -> -3.6us); R15
// showed nibbling (reg->LDS swaps) doesn't converge. This round removes the
// spill STRUCTURALLY: the per-wave live set scales with the s-slice width,
// so the block goes 8 waves x 128 cols -> 16 waves x 64 cols (1024 thr).
// Per-wave live: kb 16 + cj 16 + V 16 + avg 32 + qa/temps (+acc 16
// transient, killed by the R14 P-reread fold) ~= 115 < 128 -> no spill.
// Bonus: 4 waves/SIMD (was 2) doubles latency-hiding TLP.
//
// Geometry otherwise R9/R14-exact: block = (32 t-rows, b, 8-head half),
// grid (32,4,2) = 256 = 1/CU; K/V loaded once per head (ts==0), reused at
// ts==1; depth-1 youngest-VMEM qa/cj prefetch; lgkm-only raw barrier;
// Op/red double-buffered [2][16][.]; avg via LDS-P re-read; z=1 -> p1,
// merged in out_proj (fused). LDS = 104 KB (Op 66 + red 2 + P 36).
// ---------------------------------------------------------------------------
__global__ __launch_bounds__(1024, 1)
void attn_mfma(const __bf16* __restrict__ qTb, const __bf16* __restrict__ kTb,
               const __bf16* __restrict__ vTb, const float* __restrict__ bias,
               const int* __restrict__ mask, __bf16* __restrict__ attnb,
               float* __restrict__ avgf, __bf16* __restrict__ p1)
{
    // [0,16896): Op[2][16][528]  [16896,17408): red[2][16][16]
    // [17408,26624): P bf16 [16 waves][16][72]
    __shared__ float smem[26624];
    float* const Op0  = smem;
    float* const red0 = &smem[16896];
    __bf16* const Pbase = (__bf16*)&smem[17408];

    const int tid  = threadIdx.x;
    const int w    = tid >> 6;            // 0..15
    const int lane = tid & 63;
    const int lq   = lane & 15;
    const int quad = lane >> 4;

    // bijective XCD swizzle (R9-verified)
    const int bid = blockIdx.z * 128 + blockIdx.y * 32 + blockIdx.x;
    const int swz = (bid & 7) * 32 + (bid >> 3);
    const int t0  = (swz & 31) * 32;       // 32-row t-supertile
    const int b   = (swz >> 5) & 3;
    const int z   = swz >> 7;              // head half
    const int sbase = w * 64;              // 64-column s-slice per wave

    __bf16* const Pw = Pbase + w * 1152;   // [16][72] bf16 per wave

    // pack 16 mask bits (s = sbase + j*16 + quad*4 + r, j=0..3)
    unsigned mbits = 0;
    {
        const int* mp = mask + b * 1024 + sbase + quad * 4;
#pragma unroll
        for (int j = 0; j < 4; j++) {
            int4 m4 = *(const int4*)(mp + j * 16);
            mbits |= (unsigned)(m4.x != 0) << (j * 4 + 0);
            mbits |= (unsigned)(m4.y != 0) << (j * 4 + 1);
            mbits |= (unsigned)(m4.z != 0) << (j * 4 + 2);
            mbits |= (unsigned)(m4.w != 0) << (j * 4 + 3);
        }
    }

    // bases for this block's 8 heads (z*8 .. z*8+7), t-rows t0..t0+31
    const float* const bb = bias + (((size_t)(b * 16 + z * 8)) << 20) +
                            (((size_t)(t0 + lq)) << 10) + sbase + quad * 4;
    const __bf16* const qp0 = qTb + (((size_t)((b * 16 + z * 8) * 1024 + t0)) << 5) +
                              lq * 32 + quad * 8;
    const __bf16* const kp0 = kTb + ((size_t)(b * 16 + z * 8) << 15);
    const __bf16* const vp0 = vTb + ((size_t)(b * 16 + z * 8) << 15);

    // prologue: (head 0, ts 0) Q + bias into registers
    bf16x8 qa = *(const bf16x8*)qp0;
    f32x4 cj[4];
#pragma unroll
    for (int j = 0; j < 4; j++) cj[j] = *(const f32x4*)(bb + j * 16);

    float avg0[16] = {}, avg1[16] = {};
    bf16x8 kb[4];            // persist across the two t-subtiles of a head
    bf16x8 v0r[2], v1r[2];

    // body for one (head, t-subtile); ts is a call-site literal.
    auto body = [&](int hh, int ts, float (&avg)[16]) {
        float* const Op  = Op0  + ts * 8448;       // ts alternates 0/1
        float* const red = red0 + ts * 256;

        // K/V for this head: loaded once (ts==0), reused at ts==1.
        if (ts == 0) {
            const __bf16* kp = kp0 + ((size_t)hh << 15);
            const __bf16* vp = vp0 + ((size_t)hh << 15);
#pragma unroll
            for (int j = 0; j < 4; j++)
                kb[j] = *(const bf16x8*)(kp + (size_t)(sbase + j * 16 + lq) * 32 + quad * 8);
#pragma unroll
            for (int ks = 0; ks < 2; ks++) {
                v0r[ks] = *(const bf16x8*)(vp + (size_t)lq * 1024 + sbase + ks * 32 + quad * 8);
                v1r[ks] = *(const bf16x8*)(vp + (size_t)(16 + lq) * 1024 + sbase + ks * 32 + quad * 8);
            }
        }
        __builtin_amdgcn_sched_barrier(0);

        // QK: bias C-operands from registers (prefetched last iteration)
        f32x4 acc[4];
#pragma unroll
        for (int j = 0; j < 4; j++)
            acc[j] = __builtin_amdgcn_mfma_f32_16x16x32_bf16(kb[j], qa, cj[j], 0, 0, 0);
        __builtin_amdgcn_sched_barrier(0);

        // prefetch next iteration's Q + bias (youngest VMEM; wraps benignly)
        {
            const int hn  = (ts == 0) ? hh : ((hh + 1) & 7);
            const int tsn = ts ^ 1;
            qa = *(const bf16x8*)(qp0 + ((size_t)hn << 15) + (tsn << 9));
            const float* bn = bb + ((size_t)hn << 20) + (tsn << 14);
#pragma unroll
            for (int j = 0; j < 4; j++) cj[j] = *(const f32x4*)(bn + j * 16);
        }
        __builtin_amdgcn_sched_barrier(0);

        // exp (no max pass; scores bounded) + mask + row partial sum
        float sm = 0.f;
#pragma unroll
        for (int j = 0; j < 4; j++)
#pragma unroll
            for (int r = 0; r < 4; r++) {
                float p = __expf(acc[j][r]);
                p = ((mbits >> (j * 4 + r)) & 1u) ? 0.f : p;
                acc[j][r] = p;
                sm += p;
            }
        sm += __shfl_xor(sm, 16);
        sm += __shfl_xor(sm, 32);

        // unnormalized bf16 P into per-wave LDS region (same-wave use only).
        // acc DIES here -- the avg fold below re-reads P from LDS.
#pragma unroll
        for (int j = 0; j < 4; j++) {
            bf16x4 pv;
            pv[0] = (__bf16)acc[j][0]; pv[1] = (__bf16)acc[j][1];
            pv[2] = (__bf16)acc[j][2]; pv[3] = (__bf16)acc[j][3];
            *(bf16x4*)&Pw[lq * 72 + j * 16 + quad * 4] = pv;
        }
        if (lane < 16) red[w * 16 + lane] = sm;

        // PV: P from LDS (lgkmcnt only), V in registers
        f32x4 o0 = {0.f, 0.f, 0.f, 0.f}, o1 = {0.f, 0.f, 0.f, 0.f};
#pragma unroll
        for (int ks = 0; ks < 2; ks++) {
            bf16x8 pa = *(const bf16x8*)&Pw[lq * 72 + ks * 32 + quad * 8];
            o0 = __builtin_amdgcn_mfma_f32_16x16x32_bf16(pa, v0r[ks], o0, 0, 0, 0);
            o1 = __builtin_amdgcn_mfma_f32_16x16x32_bf16(pa, v1r[ks], o1, 0, 0, 0);
        }
#pragma unroll
        for (int r = 0; r < 4; r++) {
            Op[w * 528 + (quad * 4 + r) * 33 + lq]      = o0[r];
            Op[w * 528 + (quad * 4 + r) * 33 + 16 + lq] = o1[r];
        }

        // raw barrier: compiler fence + lgkm-only drain; prefetch stays live.
        __builtin_amdgcn_sched_barrier(0);
        asm volatile("s_waitcnt lgkmcnt(0)" ::: "memory");
        __builtin_amdgcn_s_barrier();
        __builtin_amdgcn_sched_barrier(0);

        // cross-wave reduce (16 waves): normalized O write; 512 threads
        if (tid < 512) {
            const int t = tid >> 5, d = tid & 31;
            float s = 0.f, o = 0.f;
#pragma unroll
            for (int w2 = 0; w2 < 16; w2++) s += red[w2 * 16 + t];
#pragma unroll
            for (int w2 = 0; w2 < 16; w2++) o += Op[w2 * 528 + t * 33 + d];
            attnb[((size_t)(t0 + ts * 16 + t) * 4 + b) * 512 + (z * 8 + hh) * 32 + d] =
                (__bf16)(o / s);
        }

        // inv for this lane's rows (t = ts*16+lq) + avg fold from LDS P
        float s_all = 0.f;
#pragma unroll
        for (int w2 = 0; w2 < 16; w2++) s_all += red[w2 * 16 + lq];
        const float inv = 1.0f / s_all;
#pragma unroll
        for (int j = 0; j < 4; j++) {
            bf16x4 pb = *(const bf16x4*)&Pw[lq * 72 + j * 16 + quad * 4];
#pragma unroll
            for (int r = 0; r < 4; r++)
                avg[j * 4 + r] += (float)pb[r] * inv;
        }
    };

    for (int hh = 0; hh < 8; hh++) {
        body(hh, 0, avg0);
        body(hh, 1, avg1);
    }

    // head-mean stores for both t-subtiles: z=0 fp32 direct, z=1 bf16 partial
#pragma unroll
    for (int ts = 0; ts < 2; ts++) {
        const float* avg = ts ? avg1 : avg0;
        const size_t rowbase = ((size_t)(b * 1024 + t0 + ts * 16 + lq) << 10) +
                               sbase + quad * 4;
        if (z == 0) {
            float* ap = avgf + rowbase;
#pragma unroll
            for (int j = 0; j < 4; j++) {
                f32x4 v = { avg[j * 4 + 0] * 0.0625f, avg[j * 4 + 1] * 0.0625f,
                            avg[j * 4 + 2] * 0.0625f, avg[j * 4 + 3] * 0.0625f };
                *(f32x4*)(ap + j * 16) = v;
            }
        } else {
            __bf16* pp = p1 + rowbase;
#pragma unroll
            for (int j = 0; j < 4; j++) {
                bf16x4 v;
                v[0] = (__bf16)(avg[j * 4 + 0] * 0.0625f);
                v[1] = (__bf16)(avg[j * 4 + 1] * 0.0625f);
                v[2] = (__bf16)(avg[j * 4 + 2] * 0.0625f);
                v[3] = (__bf16)(avg[j * 4 + 3] * 0.0625f);
                *(bf16x4*)(pp + j * 16) = v;
            }
        }
    }
}

// ---------------------------------------------------------------------------
extern "C" void kernel_launch(void* const* d_in, const int* in_sizes, int n_in,
                              void* d_out, int out_size, void* d_ws, size_t ws_size,
                              hipStream_t stream)
{
    const float* query     = (const float*)d_in[0];
    const float* attn_bias = (const float*)d_in[1];
    const int*   mask      = (const int*)d_in[2];
    const float* q_w       = (const float*)d_in[3];
    const float* q_b       = (const float*)d_in[4];
    const float* k_w       = (const float*)d_in[5];
    const float* k_b       = (const float*)d_in[6];
    const float* v_w       = (const float*)d_in[7];
    const float* v_b       = (const float*)d_in[8];
    const float* out_w     = (const float*)d_in[9];
    const float* out_b     = (const float*)d_in[10];

    float* out     = (float*)d_out;                 // [1024,4,512]
    float* avg_out = out + (size_t)2097152;         // [4,1024,1024]

    char* wsb = (char*)d_ws;
    __bf16* Wqb   = (__bf16*)(wsb);                         // 512 KB
    __bf16* Wkb   = (__bf16*)(wsb + ((size_t)512 << 10));
    __bf16* Wvb   = (__bf16*)(wsb + ((size_t)1 << 20));
    __bf16* Wob   = (__bf16*)(wsb + ((size_t)1 << 20) + ((size_t)512 << 10));
    __bf16* qTb   = (__bf16*)(wsb + ((size_t)2  << 20));    // 4 MB [64][1024][32]
    __bf16* kTb   = (__bf16*)(wsb + ((size_t)6  << 20));    // 4 MB [64][1024][32]
    __bf16* vTb   = (__bf16*)(wsb + ((size_t)10 << 20));    // 4 MB [64][32][1024]
    __bf16* attnb = (__bf16*)(wsb + ((size_t)14 << 20));    // 4 MB [4096][512]
    __bf16* p1    = (__bf16*)(wsb + ((size_t)18 << 20));    // 8 MB

    cvt_w<<<dim3(128, 4), dim3(256), 0, stream>>>(
        q_w, k_w, v_w, out_w, Wqb, Wkb, Wvb, Wob);

    qkv_proj<<<dim3(64, 4), dim3(256), 0, stream>>>(
        query, Wqb, Wkb, Wvb, q_b, k_b, v_b, qTb, kTb, vTb);

    attn_mfma<<<dim3(32, 4, 2), dim3(1024), 0, stream>>>(
        qTb, kTb, vTb, attn_bias, mask, attnb, avg_out, p1);

    out_proj<<<dim3(64, 36), dim3(256), 0, stream>>>(
        attnb, Wob, out_b, out, avg_out, p1);
}

// Round 17
// 155.851 us; speedup vs baseline: 1.5104x; 1.5104x over previous
//
#include <hip/hip_runtime.h>
#include <math.h>

typedef __bf16 bf16x8 __attribute__((ext_vector_type(8)));
typedef __bf16 bf16x4 __attribute__((ext_vector_type(4)));
typedef float  f32x4  __attribute__((ext_vector_type(4)));

// ---------------------------------------------------------------------------
// cvt: fp32 -> bf16 for the 4 weight matrices (512x512 each)
// ---------------------------------------------------------------------------
__global__ __launch_bounds__(256)
void cvt_w(const float* __restrict__ w0, const float* __restrict__ w1,
           const float* __restrict__ w2, const float* __restrict__ w3,
           __bf16* __restrict__ d0, __bf16* __restrict__ d1,
           __bf16* __restrict__ d2, __bf16* __restrict__ d3)
{
    const int y = blockIdx.y;
    const float* s = (y == 0) ? w0 : (y == 1) ? w1 : (y == 2) ? w2 : w3;
    __bf16*      d = (y == 0) ? d0 : (y == 1) ? d1 : (y == 2) ? d2 : d3;
    const int i = blockIdx.x * 256 + threadIdx.x;
    float4 a = *(const float4*)(s + (size_t)i * 8);
    float4 b = *(const float4*)(s + (size_t)i * 8 + 4);
    bf16x8 v;
    v[0] = (__bf16)a.x; v[1] = (__bf16)a.y; v[2] = (__bf16)a.z; v[3] = (__bf16)a.w;
    v[4] = (__bf16)b.x; v[5] = (__bf16)b.y; v[6] = (__bf16)b.z; v[7] = (__bf16)b.w;
    *(bf16x8*)(d + (size_t)i * 8) = v;
}

// ---------------------------------------------------------------------------
// Fused QKV projection, z-merged (R8-proven, +9us): one block computes Q, K
// and V for its tile; X loaded once per k-chunk feeds all three MFMA sets.
// ---------------------------------------------------------------------------
__global__ __launch_bounds__(256, 2)
void qkv_proj(const float* __restrict__ X,
              const __bf16* __restrict__ Wqb, const __bf16* __restrict__ Wkb,
              const __bf16* __restrict__ Wvb,
              const float* __restrict__ bq, const float* __restrict__ bk,
              const float* __restrict__ bv,
              __bf16* __restrict__ qTb, __bf16* __restrict__ kTb,
              __bf16* __restrict__ vTb)
{
    const int tid  = threadIdx.x;
    const int w    = tid >> 6;
    const int lane = tid & 63;
    const int lq   = lane & 15;
    const int quad = lane >> 4;
    const int n0    = blockIdx.x * 64 + (w >> 1) * 32;
    const int obase = blockIdx.y * 128 + (w & 1) * 64;

    const __bf16* const Wz[3] = { Wqb, Wkb, Wvb };

    f32x4 acc[3][2][4] = {};
    for (int k0 = 0; k0 < 512; k0 += 32) {
        bf16x8 af[2];
#pragma unroll
        for (int m = 0; m < 2; m++) {
            const float* xp = X + (size_t)(n0 + m * 16 + lq) * 512 + k0 + quad * 8;
            float4 x0 = *(const float4*)xp;
            float4 x1 = *(const float4*)(xp + 4);
            bf16x8 v;
            v[0] = (__bf16)x0.x; v[1] = (__bf16)x0.y; v[2] = (__bf16)x0.z; v[3] = (__bf16)x0.w;
            v[4] = (__bf16)x1.x; v[5] = (__bf16)x1.y; v[6] = (__bf16)x1.z; v[7] = (__bf16)x1.w;
            af[m] = v;
        }
#pragma unroll
        for (int z = 0; z < 3; z++) {
            bf16x8 bfr[4];
#pragma unroll
            for (int nn = 0; nn < 4; nn++)
                bfr[nn] = *(const bf16x8*)(Wz[z] + (size_t)(obase + nn * 16 + lq) * 512 + k0 + quad * 8);
#pragma unroll
            for (int m = 0; m < 2; m++)
#pragma unroll
                for (int nn = 0; nn < 4; nn++)
                    acc[z][m][nn] = __builtin_amdgcn_mfma_f32_16x16x32_bf16(af[m], bfr[nn], acc[z][m][nn], 0, 0, 0);
        }
    }

    const float* const ba[3] = { bq, bk, bv };
    const float scaling = 0.17677669529663687f;
#pragma unroll
    for (int z = 0; z < 3; z++)
#pragma unroll
        for (int m = 0; m < 2; m++)
#pragma unroll
            for (int nn = 0; nn < 4; nn++)
#pragma unroll
                for (int r = 0; r < 4; r++) {
                    const int n = n0 + m * 16 + quad * 4 + r;
                    const int o = obase + nn * 16 + lq;
                    float val = acc[z][m][nn][r] + ba[z][o];
                    const int t = n >> 2, b = n & 3;
                    const int h = o >> 5, d = o & 31;
                    const int bh = b * 16 + h;
                    if (z == 0)
                        qTb[(((size_t)bh * 1024 + t) << 5) + d] = (__bf16)(val * scaling);
                    else if (z == 1)
                        kTb[(((size_t)bh * 1024 + t) << 5) + d] = (__bf16)val;
                    else
                        vTb[(((size_t)bh * 32 + d) << 10) + t] = (__bf16)val;
                }
}

// ---------------------------------------------------------------------------
// Out projection (y<4) with fused avg merge (y>=4, replaces avg_add launch).
// ---------------------------------------------------------------------------
__global__ __launch_bounds__(256)
void out_proj(const __bf16* __restrict__ A, const __bf16* __restrict__ Wb,
              const float* __restrict__ bias, float* __restrict__ out,
              float* __restrict__ avg, const __bf16* __restrict__ p1)
{
    if (blockIdx.y >= 4) {
        // avg_out += p1 (bf16 partial). (64x32) blocks x 256 thr x 8 = 4194304
        const size_t i = ((size_t)((blockIdx.y - 4) * 64 + blockIdx.x) * 256 +
                          threadIdx.x) * 8;
        bf16x8 a = *(const bf16x8*)(p1 + i);
        float4 lo = *(float4*)(avg + i);
        float4 hi = *(float4*)(avg + i + 4);
        lo.x += (float)a[0]; lo.y += (float)a[1];
        lo.z += (float)a[2]; lo.w += (float)a[3];
        hi.x += (float)a[4]; hi.y += (float)a[5];
        hi.z += (float)a[6]; hi.w += (float)a[7];
        *(float4*)(avg + i)     = lo;
        *(float4*)(avg + i + 4) = hi;
        return;
    }

    const int tid  = threadIdx.x;
    const int w    = tid >> 6;
    const int lane = tid & 63;
    const int lq   = lane & 15;
    const int quad = lane >> 4;
    const int n0    = blockIdx.x * 64 + (w >> 1) * 32;
    const int obase = blockIdx.y * 128 + (w & 1) * 64;

    f32x4 acc[2][4] = {};
    for (int k0 = 0; k0 < 512; k0 += 32) {
        bf16x8 af[2], bfr[4];
#pragma unroll
        for (int m = 0; m < 2; m++)
            af[m] = *(const bf16x8*)(A + (size_t)(n0 + m * 16 + lq) * 512 + k0 + quad * 8);
#pragma unroll
        for (int nn = 0; nn < 4; nn++)
            bfr[nn] = *(const bf16x8*)(Wb + (size_t)(obase + nn * 16 + lq) * 512 + k0 + quad * 8);
#pragma unroll
        for (int m = 0; m < 2; m++)
#pragma unroll
            for (int nn = 0; nn < 4; nn++)
                acc[m][nn] = __builtin_amdgcn_mfma_f32_16x16x32_bf16(af[m], bfr[nn], acc[m][nn], 0, 0, 0);
    }
#pragma unroll
    for (int m = 0; m < 2; m++)
#pragma unroll
        for (int nn = 0; nn < 4; nn++)
#pragma unroll
            for (int r = 0; r < 4; r++) {
                const int n = n0 + m * 16 + quad * 4 + r;
                const int o = obase + nn * 16 + lq;
                out[(size_t)n * 512 + o] = acc[m][nn][r] + bias[o];
            }
}

// ---------------------------------------------------------------------------
// MFMA attention, 4-WAVE (256-thread) build.
//
// R16's counters completed the allocator rule: VGPR budget = 65536 /
// block_threads (512->128, 1024->64). The 10-round "128-VGPR wall" was
// block-size-proportional all along. 256 threads -> 256 VGPRs: the spill
// that R14 partially relieved (-32 regs -> -3.6us) disappears entirely.
//
// Block = 16 t-rows x 8 heads (z-half), 4 waves; wave owns 256 s-cols,
// processed as 2 sequential 128-col chunks so the per-chunk live set is
// exactly R14's proven size: peak ~220 < 256. Grid (64,4,2) = 512 blocks
// = 2/CU = 8 waves/CU (same TLP as R14). Proven elements kept: youngest-
// VMEM cj/qa prefetch chain (FIFO: K/V of chunk are older than the next
// cj prefetch; barrier is lgkm-only), Op/red parity double-buffer, avg
// fold via post-barrier P re-read (acc dies at P-write), z=1 -> p1 with
// fused merge in out_proj, bijective XCD swizzle (each XCD = one (b,z)).
// LDS 51.2 KB/block (2 blocks -> 102 KB/CU).
// ---------------------------------------------------------------------------
__global__ __launch_bounds__(256)
void attn_mfma(const __bf16* __restrict__ qTb, const __bf16* __restrict__ kTb,
               const __bf16* __restrict__ vTb, const float* __restrict__ bias,
               const int* __restrict__ mask, __bf16* __restrict__ attnb,
               float* __restrict__ avgf, __bf16* __restrict__ p1)
{
    // [0,4224): Op[2][4][528]  [4224,4352): red[2][4][16]
    // [4352,12800): P bf16 [4 waves][16][264]
    __shared__ float smem[12800];
    float* const Op0  = smem;
    float* const red0 = &smem[4224];
    __bf16* const Pbase = (__bf16*)&smem[4352];

    const int tid  = threadIdx.x;
    const int w    = tid >> 6;            // 0..3
    const int lane = tid & 63;
    const int lq   = lane & 15;
    const int quad = lane >> 4;

    // bijective XCD swizzle: 512 blocks -> 64-block chunk per XCD, each
    // chunk = one (b,z) pair x all 64 t-tiles (per-XCD hot K/V = 8 heads).
    const int bid = blockIdx.z * 256 + blockIdx.y * 64 + blockIdx.x;
    const int swz = (bid & 7) * 64 + (bid >> 3);
    const int t0  = (swz & 63) * 16;
    const int b   = (swz >> 6) & 3;
    const int z   = swz >> 8;              // head half
    const int sbase = w * 256;             // 256-col s-slice per wave

    __bf16* const Pw = Pbase + w * 4224;   // [16][264] bf16 per wave

    // mask bits per chunk (s = sbase + c*128 + j*16 + quad*4 + r)
    unsigned mb0 = 0, mb1 = 0;
    {
        const int* mp = mask + b * 1024 + sbase + quad * 4;
#pragma unroll
        for (int j = 0; j < 8; j++) {
            int4 m4 = *(const int4*)(mp + j * 16);
            mb0 |= (unsigned)(m4.x != 0) << (j * 4 + 0);
            mb0 |= (unsigned)(m4.y != 0) << (j * 4 + 1);
            mb0 |= (unsigned)(m4.z != 0) << (j * 4 + 2);
            mb0 |= (unsigned)(m4.w != 0) << (j * 4 + 3);
        }
#pragma unroll
        for (int j = 0; j < 8; j++) {
            int4 m4 = *(const int4*)(mp + 128 + j * 16);
            mb1 |= (unsigned)(m4.x != 0) << (j * 4 + 0);
            mb1 |= (unsigned)(m4.y != 0) << (j * 4 + 1);
            mb1 |= (unsigned)(m4.z != 0) << (j * 4 + 2);
            mb1 |= (unsigned)(m4.w != 0) << (j * 4 + 3);
        }
    }

    // bases for this block's 8 heads (z*8 .. z*8+7), t-rows t0..t0+15
    const float* const bb = bias + (((size_t)(b * 16 + z * 8)) << 20) +
                            (((size_t)(t0 + lq)) << 10) + sbase + quad * 4;
    const __bf16* const qp0 = qTb + (((size_t)((b * 16 + z * 8) * 1024 + t0)) << 5) +
                              lq * 32 + quad * 8;
    const __bf16* const kp0 = kTb + ((size_t)(b * 16 + z * 8) << 15);
    const __bf16* const vp0 = vTb + ((size_t)(b * 16 + z * 8) << 15);

    // prologue: head 0 Q + chunk-0 bias into registers
    bf16x8 qa = *(const bf16x8*)qp0;
    f32x4 cj[8];
#pragma unroll
    for (int j = 0; j < 8; j++) cj[j] = *(const f32x4*)(bb + j * 16);

    float avgc[2][32] = {};

    for (int hh = 0; hh < 8; hh++) {
        float* const Op  = Op0  + (hh & 1) * 2112;
        float* const red = red0 + (hh & 1) * 64;
        const __bf16* kp = kp0 + ((size_t)hh << 15);
        const __bf16* vp = vp0 + ((size_t)hh << 15);

        float sm = 0.f;
        f32x4 o0 = {0.f, 0.f, 0.f, 0.f}, o1 = {0.f, 0.f, 0.f, 0.f};

        // one 128-col chunk; c is a call-site literal.
        auto chunk = [&](int c) {
            const int cb = sbase + c * 128;
            const unsigned mbits = c ? mb1 : mb0;

            // K/V for this chunk (oldest VMEM of the chunk body)
            bf16x8 kb[8];
#pragma unroll
            for (int j = 0; j < 8; j++)
                kb[j] = *(const bf16x8*)(kp + (size_t)(cb + j * 16 + lq) * 32 + quad * 8);
            bf16x8 v0r[4], v1r[4];
#pragma unroll
            for (int ks = 0; ks < 4; ks++) {
                v0r[ks] = *(const bf16x8*)(vp + (size_t)lq * 1024 + cb + ks * 32 + quad * 8);
                v1r[ks] = *(const bf16x8*)(vp + (size_t)(16 + lq) * 1024 + cb + ks * 32 + quad * 8);
            }
            __builtin_amdgcn_sched_barrier(0);

            // QK: cj prefetched one body earlier; kb/V this body (older than
            // the next prefetch below)
            f32x4 acc[8];
#pragma unroll
            for (int j = 0; j < 8; j++)
                acc[j] = __builtin_amdgcn_mfma_f32_16x16x32_bf16(kb[j], qa, cj[j], 0, 0, 0);
            __builtin_amdgcn_sched_barrier(0);

            // prefetch next body's bias (+ next head's Q at c==1): youngest
            {
                if (c == 0) {
                    const float* bn = bb + 128;
#pragma unroll
                    for (int j = 0; j < 8; j++) cj[j] = *(const f32x4*)(bn + ((size_t)hh << 20) + j * 16);
                } else {
                    const int hn = (hh + 1) & 7;
                    qa = *(const bf16x8*)(qp0 + ((size_t)hn << 15));
                    const float* bn = bb + ((size_t)hn << 20);
#pragma unroll
                    for (int j = 0; j < 8; j++) cj[j] = *(const f32x4*)(bn + j * 16);
                }
            }
            __builtin_amdgcn_sched_barrier(0);

            // exp (no max pass; scores bounded) + mask + row partial sum
#pragma unroll
            for (int j = 0; j < 8; j++)
#pragma unroll
                for (int r = 0; r < 4; r++) {
                    float p = __expf(acc[j][r]);
                    p = ((mbits >> (j * 4 + r)) & 1u) ? 0.f : p;
                    acc[j][r] = p;
                    sm += p;
                }

            // unnormalized bf16 P into per-wave LDS (acc dies here; avg fold
            // re-reads P after the barrier)
#pragma unroll
            for (int j = 0; j < 8; j++) {
                bf16x4 pv;
                pv[0] = (__bf16)acc[j][0]; pv[1] = (__bf16)acc[j][1];
                pv[2] = (__bf16)acc[j][2]; pv[3] = (__bf16)acc[j][3];
                *(bf16x4*)&Pw[lq * 264 + c * 128 + j * 16 + quad * 4] = pv;
            }

            // PV accumulate: P from LDS (lgkmcnt only), V in registers
#pragma unroll
            for (int ks = 0; ks < 4; ks++) {
                bf16x8 pa = *(const bf16x8*)&Pw[lq * 264 + c * 128 + ks * 32 + quad * 8];
                o0 = __builtin_amdgcn_mfma_f32_16x16x32_bf16(pa, v0r[ks], o0, 0, 0, 0);
                o1 = __builtin_amdgcn_mfma_f32_16x16x32_bf16(pa, v1r[ks], o1, 0, 0, 0);
            }
        };

        chunk(0);
        chunk(1);

        // row sum across quads; stash partials
        sm += __shfl_xor(sm, 16);
        sm += __shfl_xor(sm, 32);
        if (lane < 16) red[w * 16 + lane] = sm;
#pragma unroll
        for (int r = 0; r < 4; r++) {
            Op[w * 528 + (quad * 4 + r) * 33 + lq]      = o0[r];
            Op[w * 528 + (quad * 4 + r) * 33 + 16 + lq] = o1[r];
        }

        // raw barrier: lgkm-only drain; bias/Q prefetch (VMEM) stays live.
        __builtin_amdgcn_sched_barrier(0);
        asm volatile("s_waitcnt lgkmcnt(0)" ::: "memory");
        __builtin_amdgcn_s_barrier();
        __builtin_amdgcn_sched_barrier(0);

        // cross-wave reduce (4 waves): 512 outputs over 256 threads
#pragma unroll
        for (int rep = 0; rep < 2; rep++) {
            const int idx = rep * 256 + tid;
            const int t = idx >> 5, d = idx & 31;
            float s = 0.f, o = 0.f;
#pragma unroll
            for (int w2 = 0; w2 < 4; w2++) s += red[w2 * 16 + t];
#pragma unroll
            for (int w2 = 0; w2 < 4; w2++) o += Op[w2 * 528 + t * 33 + d];
            attnb[((size_t)(t0 + t) * 4 + b) * 512 + (z * 8 + hh) * 32 + d] =
                (__bf16)(o / s);
        }

        // inv for this lane's rows (t = lq) + avg fold from LDS P (both chunks)
        float s_all = 0.f;
#pragma unroll
        for (int w2 = 0; w2 < 4; w2++) s_all += red[w2 * 16 + lq];
        const float inv = 1.0f / s_all;
#pragma unroll
        for (int c = 0; c < 2; c++)
#pragma unroll
            for (int j = 0; j < 8; j++) {
                bf16x4 pb = *(const bf16x4*)&Pw[lq * 264 + c * 128 + j * 16 + quad * 4];
#pragma unroll
                for (int r = 0; r < 4; r++)
                    avgc[c][j * 4 + r] += (float)pb[r] * inv;
            }
    }

    // head-mean stores: z=0 fp32 direct, z=1 bf16 partial (both chunks)
    const size_t rowbase = ((size_t)(b * 1024 + t0 + lq) << 10) + sbase + quad * 4;
    if (z == 0) {
        float* ap = avgf + rowbase;
#pragma unroll
        for (int c = 0; c < 2; c++)
#pragma unroll
            for (int j = 0; j < 8; j++) {
                f32x4 v = { avgc[c][j * 4 + 0] * 0.0625f, avgc[c][j * 4 + 1] * 0.0625f,
                            avgc[c][j * 4 + 2] * 0.0625f, avgc[c][j * 4 + 3] * 0.0625f };
                *(f32x4*)(ap + c * 128 + j * 16) = v;
            }
    } else {
        __bf16* pp = p1 + rowbase;
#pragma unroll
        for (int c = 0; c < 2; c++)
#pragma unroll
            for (int j = 0; j < 8; j++) {
                bf16x4 v;
                v[0] = (__bf16)(avgc[c][j * 4 + 0] * 0.0625f);
                v[1] = (__bf16)(avgc[c][j * 4 + 1] * 0.0625f);
                v[2] = (__bf16)(avgc[c][j * 4 + 2] * 0.0625f);
                v[3] = (__bf16)(avgc[c][j * 4 + 3] * 0.0625f);
                *(bf16x4*)(pp + c * 128 + j * 16) = v;
            }
    }
}

// ---------------------------------------------------------------------------
extern "C" void kernel_launch(void* const* d_in, const int* in_sizes, int n_in,
                              void* d_out, int out_size, void* d_ws, size_t ws_size,
                              hipStream_t stream)
{
    const float* query     = (const float*)d_in[0];
    const float* attn_bias = (const float*)d_in[1];
    const int*   mask      = (const int*)d_in[2];
    const float* q_w       = (const float*)d_in[3];
    const float* q_b       = (const float*)d_in[4];
    const float* k_w       = (const float*)d_in[5];
    const float* k_b       = (const float*)d_in[6];
    const float* v_w       = (const float*)d_in[7];
    const float* v_b       = (const float*)d_in[8];
    const float* out_w     = (const float*)d_in[9];
    const float* out_b     = (const float*)d_in[10];

    float* out     = (float*)d_out;                 // [1024,4,512]
    float* avg_out = out + (size_t)2097152;         // [4,1024,1024]

    char* wsb = (char*)d_ws;
    __bf16* Wqb   = (__bf16*)(wsb);                         // 512 KB
    __bf16* Wkb   = (__bf16*)(wsb + ((size_t)512 << 10));
    __bf16* Wvb   = (__bf16*)(wsb + ((size_t)1 << 20));
    __bf16* Wob   = (__bf16*)(wsb + ((size_t)1 << 20) + ((size_t)512 << 10));
    __bf16* qTb   = (__bf16*)(wsb + ((size_t)2  << 20));    // 4 MB [64][1024][32]
    __bf16* kTb   = (__bf16*)(wsb + ((size_t)6  << 20));    // 4 MB [64][1024][32]
    __bf16* vTb   = (__bf16*)(wsb + ((size_t)10 << 20));    // 4 MB [64][32][1024]
    __bf16* attnb = (__bf16*)(wsb + ((size_t)14 << 20));    // 4 MB [4096][512]
    __bf16* p1    = (__bf16*)(wsb + ((size_t)18 << 20));    // 8 MB

    cvt_w<<<dim3(128, 4), dim3(256), 0, stream>>>(
        q_w, k_w, v_w, out_w, Wqb, Wkb, Wvb, Wob);

    qkv_proj<<<dim3(64, 4), dim3(256), 0, stream>>>(
        query, Wqb, Wkb, Wvb, q_b, k_b, v_b, qTb, kTb, vTb);

    attn_mfma<<<dim3(64, 4, 2), dim3(256), 0, stream>>>(
        qTb, kTb, vTb, attn_bias, mask, attnb, avg_out, p1);

    out_proj<<<dim3(64, 36), dim3(256), 0, stream>>>(
        attnb, Wob, out_b, out, avg_out, p1);
}

// Round 18
// 141.313 us; speedup vs baseline: 1.6658x; 1.1029x over previous
//
#include <hip/hip_runtime.h>
#include <math.h>

typedef __bf16 bf16x8 __attribute__((ext_vector_type(8)));
typedef __bf16 bf16x4 __attribute__((ext_vector_type(4)));
typedef float  f32x4  __attribute__((ext_vector_type(4)));

// ---------------------------------------------------------------------------
// cvt: fp32 -> bf16 for the 4 weight matrices (512x512 each)
// ---------------------------------------------------------------------------
__global__ __launch_bounds__(256)
void cvt_w(const float* __restrict__ w0, const float* __restrict__ w1,
           const float* __restrict__ w2, const float* __restrict__ w3,
           __bf16* __restrict__ d0, __bf16* __restrict__ d1,
           __bf16* __restrict__ d2, __bf16* __restrict__ d3)
{
    const int y = blockIdx.y;
    const float* s = (y == 0) ? w0 : (y == 1) ? w1 : (y == 2) ? w2 : w3;
    __bf16*      d = (y == 0) ? d0 : (y == 1) ? d1 : (y == 2) ? d2 : d3;
    const int i = blockIdx.x * 256 + threadIdx.x;
    float4 a = *(const float4*)(s + (size_t)i * 8);
    float4 b = *(const float4*)(s + (size_t)i * 8 + 4);
    bf16x8 v;
    v[0] = (__bf16)a.x; v[1] = (__bf16)a.y; v[2] = (__bf16)a.z; v[3] = (__bf16)a.w;
    v[4] = (__bf16)b.x; v[5] = (__bf16)b.y; v[6] = (__bf16)b.z; v[7] = (__bf16)b.w;
    *(bf16x8*)(d + (size_t)i * 8) = v;
}

// ---------------------------------------------------------------------------
// Fused QKV projection, z-merged (R8-proven, +9us): one block computes Q, K
// and V for its tile; X loaded once per k-chunk feeds all three MFMA sets.
// ---------------------------------------------------------------------------
__global__ __launch_bounds__(256, 2)
void qkv_proj(const float* __restrict__ X,
              const __bf16* __restrict__ Wqb, const __bf16* __restrict__ Wkb,
              const __bf16* __restrict__ Wvb,
              const float* __restrict__ bq, const float* __restrict__ bk,
              const float* __restrict__ bv,
              __bf16* __restrict__ qTb, __bf16* __restrict__ kTb,
              __bf16* __restrict__ vTb)
{
    const int tid  = threadIdx.x;
    const int w    = tid >> 6;
    const int lane = tid & 63;
    const int lq   = lane & 15;
    const int quad = lane >> 4;
    const int n0    = blockIdx.x * 64 + (w >> 1) * 32;
    const int obase = blockIdx.y * 128 + (w & 1) * 64;

    const __bf16* const Wz[3] = { Wqb, Wkb, Wvb };

    f32x4 acc[3][2][4] = {};
    for (int k0 = 0; k0 < 512; k0 += 32) {
        bf16x8 af[2];
#pragma unroll
        for (int m = 0; m < 2; m++) {
            const float* xp = X + (size_t)(n0 + m * 16 + lq) * 512 + k0 + quad * 8;
            float4 x0 = *(const float4*)xp;
            float4 x1 = *(const float4*)(xp + 4);
            bf16x8 v;
            v[0] = (__bf16)x0.x; v[1] = (__bf16)x0.y; v[2] = (__bf16)x0.z; v[3] = (__bf16)x0.w;
            v[4] = (__bf16)x1.x; v[5] = (__bf16)x1.y; v[6] = (__bf16)x1.z; v[7] = (__bf16)x1.w;
            af[m] = v;
        }
#pragma unroll
        for (int z = 0; z < 3; z++) {
            bf16x8 bfr[4];
#pragma unroll
            for (int nn = 0; nn < 4; nn++)
                bfr[nn] = *(const bf16x8*)(Wz[z] + (size_t)(obase + nn * 16 + lq) * 512 + k0 + quad * 8);
#pragma unroll
            for (int m = 0; m < 2; m++)
#pragma unroll
                for (int nn = 0; nn < 4; nn++)
                    acc[z][m][nn] = __builtin_amdgcn_mfma_f32_16x16x32_bf16(af[m], bfr[nn], acc[z][m][nn], 0, 0, 0);
        }
    }

    const float* const ba[3] = { bq, bk, bv };
    const float scaling = 0.17677669529663687f;
#pragma unroll
    for (int z = 0; z < 3; z++)
#pragma unroll
        for (int m = 0; m < 2; m++)
#pragma unroll
            for (int nn = 0; nn < 4; nn++)
#pragma unroll
                for (int r = 0; r < 4; r++) {
                    const int n = n0 + m * 16 + quad * 4 + r;
                    const int o = obase + nn * 16 + lq;
                    float val = acc[z][m][nn][r] + ba[z][o];
                    const int t = n >> 2, b = n & 3;
                    const int h = o >> 5, d = o & 31;
                    const int bh = b * 16 + h;
                    if (z == 0)
                        qTb[(((size_t)bh * 1024 + t) << 5) + d] = (__bf16)(val * scaling);
                    else if (z == 1)
                        kTb[(((size_t)bh * 1024 + t) << 5) + d] = (__bf16)val;
                    else
                        vTb[(((size_t)bh * 32 + d) << 10) + t] = (__bf16)val;
                }
}

// ---------------------------------------------------------------------------
// Out projection (y<4) with fused avg merge (y>=4, replaces avg_add launch).
// ---------------------------------------------------------------------------
__global__ __launch_bounds__(256)
void out_proj(const __bf16* __restrict__ A, const __bf16* __restrict__ Wb,
              const float* __restrict__ bias, float* __restrict__ out,
              float* __restrict__ avg, const __bf16* __restrict__ p1)
{
    if (blockIdx.y >= 4) {
        // avg_out += p1 (bf16 partial). (64x32) blocks x 256 thr x 8 = 4194304
        const size_t i = ((size_t)((blockIdx.y - 4) * 64 + blockIdx.x) * 256 +
                          threadIdx.x) * 8;
        bf16x8 a = *(const bf16x8*)(p1 + i);
        float4 lo = *(float4*)(avg + i);
        float4 hi = *(float4*)(avg + i + 4);
        lo.x += (float)a[0]; lo.y += (float)a[1];
        lo.z += (float)a[2]; lo.w += (float)a[3];
        hi.x += (float)a[4]; hi.y += (float)a[5];
        hi.z += (float)a[6]; hi.w += (float)a[7];
        *(float4*)(avg + i)     = lo;
        *(float4*)(avg + i + 4) = hi;
        return;
    }

    const int tid  = threadIdx.x;
    const int w    = tid >> 6;
    const int lane = tid & 63;
    const int lq   = lane & 15;
    const int quad = lane >> 4;
    const int n0    = blockIdx.x * 64 + (w >> 1) * 32;
    const int obase = blockIdx.y * 128 + (w & 1) * 64;

    f32x4 acc[2][4] = {};
    for (int k0 = 0; k0 < 512; k0 += 32) {
        bf16x8 af[2], bfr[4];
#pragma unroll
        for (int m = 0; m < 2; m++)
            af[m] = *(const bf16x8*)(A + (size_t)(n0 + m * 16 + lq) * 512 + k0 + quad * 8);
#pragma unroll
        for (int nn = 0; nn < 4; nn++)
            bfr[nn] = *(const bf16x8*)(Wb + (size_t)(obase + nn * 16 + lq) * 512 + k0 + quad * 8);
#pragma unroll
        for (int m = 0; m < 2; m++)
#pragma unroll
            for (int nn = 0; nn < 4; nn++)
                acc[m][nn] = __builtin_amdgcn_mfma_f32_16x16x32_bf16(af[m], bfr[nn], acc[m][nn], 0, 0, 0);
    }
#pragma unroll
    for (int m = 0; m < 2; m++)
#pragma unroll
        for (int nn = 0; nn < 4; nn++)
#pragma unroll
            for (int r = 0; r < 4; r++) {
                const int n = n0 + m * 16 + quad * 4 + r;
                const int o = obase + nn * 16 + lq;
                out[(size_t)n * 512 + o] = acc[m][nn][r] + bias[o];
            }
}

// ---------------------------------------------------------------------------
// MFMA attention = session champion (R14, 141.5us). R9 geometry (32-row
// t-supertile, K/V loaded once per head and reused across both 16-row
// subtiles, z head-half split) + R14 register diet (avg fold re-reads the
// bf16 P from LDS after the barrier so acc[8] dies at the P-write). The
// VGPR budget is block-size-proportional (65536/threads -> 128 here);
// R15-R17 established that this configuration's moderate-spill/low-traffic
// point beats both the spill-free/double-traffic 256-thread variant and
// accumulator-offload variants. Depth-1 youngest-VMEM qa/cj prefetch,
// lgkm-only raw barrier, Op/red parity double-buffer, bijective XCD swizzle.
// ---------------------------------------------------------------------------
__global__ __attribute__((amdgpu_waves_per_eu(2, 2))) __launch_bounds__(512)
void attn_mfma(const __bf16* __restrict__ qTb, const __bf16* __restrict__ kTb,
               const __bf16* __restrict__ vTb, const float* __restrict__ bias,
               const int* __restrict__ mask, __bf16* __restrict__ attnb,
               float* __restrict__ avgf, __bf16* __restrict__ p1)
{
    // [0,8448): Op[2][8][528]  [8448,8704): red[2][8][16]
    // [8704,17408): P bf16 [8][16*136].  Padded >80KB (R7/R9 environment).
    __shared__ float smem[20800];
    float* const Op0  = smem;
    float* const red0 = &smem[8448];
    __bf16* const Pbase = (__bf16*)&smem[8704];

    const int tid  = threadIdx.x;
    const int w    = tid >> 6;
    const int lane = tid & 63;
    const int lq   = lane & 15;
    const int quad = lane >> 4;

    // bijective XCD swizzle (R9-verified)
    const int bid = blockIdx.z * 128 + blockIdx.y * 32 + blockIdx.x;
    const int swz = (bid & 7) * 32 + (bid >> 3);
    const int t0  = (swz & 31) * 32;       // 32-row t-supertile
    const int b   = (swz >> 5) & 3;
    const int z   = swz >> 7;              // head half
    const int sbase = w * 128;

    __bf16* const Pw = Pbase + w * 2176;   // 16*136 bf16 per wave

    // pack 32 mask bits (s = sbase + j*16 + quad*4 + r); shared by both ts
    unsigned mbits = 0;
    {
        const int* mp = mask + b * 1024 + sbase + quad * 4;
#pragma unroll
        for (int j = 0; j < 8; j++) {
            int4 m4 = *(const int4*)(mp + j * 16);
            mbits |= (unsigned)(m4.x != 0) << (j * 4 + 0);
            mbits |= (unsigned)(m4.y != 0) << (j * 4 + 1);
            mbits |= (unsigned)(m4.z != 0) << (j * 4 + 2);
            mbits |= (unsigned)(m4.w != 0) << (j * 4 + 3);
        }
    }

    // bases for this block's 8 heads (z*8 .. z*8+7), t-rows t0..t0+31
    const float* const bb = bias + (((size_t)(b * 16 + z * 8)) << 20) +
                            (((size_t)(t0 + lq)) << 10) + sbase + quad * 4;
    const __bf16* const qp0 = qTb + (((size_t)((b * 16 + z * 8) * 1024 + t0)) << 5) +
                              lq * 32 + quad * 8;
    const __bf16* const kp0 = kTb + ((size_t)(b * 16 + z * 8) << 15);
    const __bf16* const vp0 = vTb + ((size_t)(b * 16 + z * 8) << 15);

    // prologue: (head 0, ts 0) Q + bias into registers
    bf16x8 qa = *(const bf16x8*)qp0;
    f32x4 cj[8];
#pragma unroll
    for (int j = 0; j < 8; j++) cj[j] = *(const f32x4*)(bb + j * 16);

    float avg0[32] = {}, avg1[32] = {};
    bf16x8 kb[8];            // persist across the two t-subtiles of a head
    bf16x8 v0r[4], v1r[4];

    // body for one (head, t-subtile); ts is a call-site literal.
    auto body = [&](int hh, int ts, float (&avg)[32]) {
        float* const Op  = Op0  + ts * 4224;       // ts alternates 0/1
        float* const red = red0 + ts * 128;

        // K/V for this head: loaded once (ts==0), reused at ts==1.
        if (ts == 0) {
            const __bf16* kp = kp0 + ((size_t)hh << 15);
            const __bf16* vp = vp0 + ((size_t)hh << 15);
#pragma unroll
            for (int j = 0; j < 8; j++)
                kb[j] = *(const bf16x8*)(kp + (size_t)(sbase + j * 16 + lq) * 32 + quad * 8);
#pragma unroll
            for (int ks = 0; ks < 4; ks++) {
                v0r[ks] = *(const bf16x8*)(vp + (size_t)lq * 1024 + sbase + ks * 32 + quad * 8);
                v1r[ks] = *(const bf16x8*)(vp + (size_t)(16 + lq) * 1024 + sbase + ks * 32 + quad * 8);
            }
        }
        __builtin_amdgcn_sched_barrier(0);

        // QK: bias C-operands from registers (prefetched last iteration)
        f32x4 acc[8];
#pragma unroll
        for (int j = 0; j < 8; j++)
            acc[j] = __builtin_amdgcn_mfma_f32_16x16x32_bf16(kb[j], qa, cj[j], 0, 0, 0);
        __builtin_amdgcn_sched_barrier(0);

        // prefetch next iteration's Q + bias (youngest VMEM; wraps benignly)
        {
            const int hn  = (ts == 0) ? hh : ((hh + 1) & 7);
            const int tsn = ts ^ 1;
            qa = *(const bf16x8*)(qp0 + ((size_t)hn << 15) + (tsn << 9));
            const float* bn = bb + ((size_t)hn << 20) + (tsn << 14);
#pragma unroll
            for (int j = 0; j < 8; j++) cj[j] = *(const f32x4*)(bn + j * 16);
        }
        __builtin_amdgcn_sched_barrier(0);

        // exp (no max pass; scores bounded) + mask + row partial sum
        float sm = 0.f;
#pragma unroll
        for (int j = 0; j < 8; j++)
#pragma unroll
            for (int r = 0; r < 4; r++) {
                float p = __expf(acc[j][r]);
                p = ((mbits >> (j * 4 + r)) & 1u) ? 0.f : p;
                acc[j][r] = p;
                sm += p;
            }
        sm += __shfl_xor(sm, 16);
        sm += __shfl_xor(sm, 32);

        // unnormalized bf16 P into per-wave LDS region (same-wave use only).
        // acc DIES here -- the avg fold below re-reads P from LDS.
#pragma unroll
        for (int j = 0; j < 8; j++) {
            bf16x4 pv;
            pv[0] = (__bf16)acc[j][0]; pv[1] = (__bf16)acc[j][1];
            pv[2] = (__bf16)acc[j][2]; pv[3] = (__bf16)acc[j][3];
            *(bf16x4*)&Pw[lq * 136 + j * 16 + quad * 4] = pv;
        }
        if (lane < 16) red[w * 16 + lane] = sm;

        // PV: P from LDS (lgkmcnt only), V in registers
        f32x4 o0 = {0.f, 0.f, 0.f, 0.f}, o1 = {0.f, 0.f, 0.f, 0.f};
#pragma unroll
        for (int ks = 0; ks < 4; ks++) {
            bf16x8 pa = *(const bf16x8*)&Pw[lq * 136 + ks * 32 + quad * 8];
            o0 = __builtin_amdgcn_mfma_f32_16x16x32_bf16(pa, v0r[ks], o0, 0, 0, 0);
            o1 = __builtin_amdgcn_mfma_f32_16x16x32_bf16(pa, v1r[ks], o1, 0, 0, 0);
        }
#pragma unroll
        for (int r = 0; r < 4; r++) {
            Op[w * 528 + (quad * 4 + r) * 33 + lq]      = o0[r];
            Op[w * 528 + (quad * 4 + r) * 33 + 16 + lq] = o1[r];
        }

        // raw barrier: compiler fence + lgkm-only drain; prefetch stays live.
        __builtin_amdgcn_sched_barrier(0);
        asm volatile("s_waitcnt lgkmcnt(0)" ::: "memory");
        __builtin_amdgcn_s_barrier();
        __builtin_amdgcn_sched_barrier(0);

        // cross-wave reduce: normalized O write
        {
            const int t = tid >> 5, d = tid & 31;
            float s = 0.f, o = 0.f;
#pragma unroll
            for (int w2 = 0; w2 < 8; w2++) s += red[w2 * 16 + t];
#pragma unroll
            for (int w2 = 0; w2 < 8; w2++) o += Op[w2 * 528 + t * 33 + d];
            attnb[((size_t)(t0 + ts * 16 + t) * 4 + b) * 512 + (z * 8 + hh) * 32 + d] =
                (__bf16)(o / s);
        }

        // inv for this lane's rows (t = ts*16+lq) + avg fold from LDS P
        // (this wave's own slice; next overwrite is this wave's next P-write)
        float s_all = 0.f;
#pragma unroll
        for (int w2 = 0; w2 < 8; w2++) s_all += red[w2 * 16 + lq];
        const float inv = 1.0f / s_all;
#pragma unroll
        for (int j = 0; j < 8; j++) {
            bf16x4 pb = *(const bf16x4*)&Pw[lq * 136 + j * 16 + quad * 4];
#pragma unroll
            for (int r = 0; r < 4; r++)
                avg[j * 4 + r] += (float)pb[r] * inv;
        }
    };

    for (int hh = 0; hh < 8; hh++) {
        body(hh, 0, avg0);
        body(hh, 1, avg1);
    }

    // head-mean stores for both t-subtiles: z=0 fp32 direct, z=1 bf16 partial
#pragma unroll
    for (int ts = 0; ts < 2; ts++) {
        const float* avg = ts ? avg1 : avg0;
        const size_t rowbase = ((size_t)(b * 1024 + t0 + ts * 16 + lq) << 10) +
                               sbase + quad * 4;
        if (z == 0) {
            float* ap = avgf + rowbase;
#pragma unroll
            for (int j = 0; j < 8; j++) {
                f32x4 v = { avg[j * 4 + 0] * 0.0625f, avg[j * 4 + 1] * 0.0625f,
                            avg[j * 4 + 2] * 0.0625f, avg[j * 4 + 3] * 0.0625f };
                *(f32x4*)(ap + j * 16) = v;
            }
        } else {
            __bf16* pp = p1 + rowbase;
#pragma unroll
            for (int j = 0; j < 8; j++) {
                bf16x4 v;
                v[0] = (__bf16)(avg[j * 4 + 0] * 0.0625f);
                v[1] = (__bf16)(avg[j * 4 + 1] * 0.0625f);
                v[2] = (__bf16)(avg[j * 4 + 2] * 0.0625f);
                v[3] = (__bf16)(avg[j * 4 + 3] * 0.0625f);
                *(bf16x4*)(pp + j * 16) = v;
            }
        }
    }
}

// ---------------------------------------------------------------------------
extern "C" void kernel_launch(void* const* d_in, const int* in_sizes, int n_in,
                              void* d_out, int out_size, void* d_ws, size_t ws_size,
                              hipStream_t stream)
{
    const float* query     = (const float*)d_in[0];
    const float* attn_bias = (const float*)d_in[1];
    const int*   mask      = (const int*)d_in[2];
    const float* q_w       = (const float*)d_in[3];
    const float* q_b       = (const float*)d_in[4];
    const float* k_w       = (const float*)d_in[5];
    const float* k_b       = (const float*)d_in[6];
    const float* v_w       = (const float*)d_in[7];
    const float* v_b       = (const float*)d_in[8];
    const float* out_w     = (const float*)d_in[9];
    const float* out_b     = (const float*)d_in[10];

    float* out     = (float*)d_out;                 // [1024,4,512]
    float* avg_out = out + (size_t)2097152;         // [4,1024,1024]

    char* wsb = (char*)d_ws;
    __bf16* Wqb   = (__bf16*)(wsb);                         // 512 KB
    __bf16* Wkb   = (__bf16*)(wsb + ((size_t)512 << 10));
    __bf16* Wvb   = (__bf16*)(wsb + ((size_t)1 << 20));
    __bf16* Wob   = (__bf16*)(wsb + ((size_t)1 << 20) + ((size_t)512 << 10));
    __bf16* qTb   = (__bf16*)(wsb + ((size_t)2  << 20));    // 4 MB [64][1024][32]
    __bf16* kTb   = (__bf16*)(wsb + ((size_t)6  << 20));    // 4 MB [64][1024][32]
    __bf16* vTb   = (__bf16*)(wsb + ((size_t)10 << 20));    // 4 MB [64][32][1024]
    __bf16* attnb = (__bf16*)(wsb + ((size_t)14 << 20));    // 4 MB [4096][512]
    __bf16* p1    = (__bf16*)(wsb + ((size_t)18 << 20));    // 8 MB

    cvt_w<<<dim3(128, 4), dim3(256), 0, stream>>>(
        q_w, k_w, v_w, out_w, Wqb, Wkb, Wvb, Wob);

    qkv_proj<<<dim3(64, 4), dim3(256), 0, stream>>>(
        query, Wqb, Wkb, Wvb, q_b, k_b, v_b, qTb, kTb, vTb);

    attn_mfma<<<dim3(32, 4, 2), dim3(512), 0, stream>>>(
        qTb, kTb, vTb, attn_bias, mask, attnb, avg_out, p1);

    out_proj<<<dim3(64, 36), dim3(256), 0, stream>>>(
        attnb, Wob, out_b, out, avg_out, p1);
}